// Round 11
// baseline (1262.850 us; speedup 1.0000x reference)
//
#include <hip/hip_runtime.h>

#define NSEQ 1028
#define TT   256
#define CC   64
#define HH   256
#define SLABE 32768            // elems per kt slab: 8 waves * 8 ct * 512
// xg-path geometry (K=256)
#define XROW 528               // A row bytes: 256*2 + 16 pad
#define XG_A (16*XROW)         // 8448 per A buffer
#define XG_LDS (2*XG_A + 2*SLABE*2)       // 16896 + 131072 = 147968
// fallback geometry (K=320)
#define AROWB 656
#define FB_LDS (2*16*AROWB + 2*SLABE*2)   // 152064
#define OUTP_LDS (128*264*2 + 64*264*2)   // 101376

typedef unsigned short u16;
typedef float  f32x4 __attribute__((ext_vector_type(4)));
typedef __bf16 v8bf  __attribute__((ext_vector_type(8)));

__device__ __forceinline__ u16 f2bf(float f){
  unsigned u = __builtin_bit_cast(unsigned, f);
  u += 0x7FFFu + ((u >> 16) & 1u);
  return (u16)(u >> 16);
}
__device__ __forceinline__ float sigm(float x){
  float t = __builtin_amdgcn_exp2f(-1.4426950408889634f * x);
  return __builtin_amdgcn_rcpf(1.0f + t);
}
__device__ __forceinline__ float tanh_f(float x){
  float a = __builtin_fabsf(x);
  float t = __builtin_amdgcn_exp2f(-2.885390081777927f * a);
  float r = (1.0f - t) * __builtin_amdgcn_rcpf(1.0f + t);
  return __builtin_copysignf(r, x);
}
__device__ __forceinline__ void mfma_a(f32x4& d, v8bf a, v8bf b){
  asm("v_mfma_f32_16x16x32_bf16 %0, %1, %2, %0" : "+v"(d) : "v"(a), "a"(b));
}
__device__ __forceinline__ void mfma_v(f32x4& d, v8bf a, v8bf b){
  asm("v_mfma_f32_16x16x32_bf16 %0, %1, %2, %0" : "+v"(d) : "v"(a), "v"(b));
}
// barrier without vmcnt drain: LDS visibility only (globals stay in flight)
__device__ __forceinline__ void soft_barrier(){
  asm volatile("s_waitcnt lgkmcnt(0)" ::: "memory");
  __builtin_amdgcn_sched_barrier(0);
  __builtin_amdgcn_s_barrier();
  __builtin_amdgcn_sched_barrier(0);
}

// ---- pack W = [W_hh | W_ih] into per-(kt,wave,ct) MFMA B-frags, bf16
__global__ void k_pack_w(const float* __restrict__ Whh, const float* __restrict__ Wih,
                         u16* __restrict__ wpack){
  int idx = blockIdx.x*256 + threadIdx.x;
  if (idx >= 10*SLABE) return;                 // 327680
  int j    = idx & 7;
  int lane = (idx >> 3) & 63;
  int ct   = (idx >> 9) & 7;
  int w    = (idx >> 12) & 7;
  int kt   = idx >> 15;
  int col  = (ct >> 1)*256 + w*32 + (ct & 1)*16 + (lane & 15);
  int k    = kt*32 + (lane >> 4)*8 + j;
  float v  = (k < 256) ? Whh[col*256 + k] : Wih[col*64 + (k - 256)];
  wpack[idx] = f2bf(v);
}

__global__ void k_bias(const float* __restrict__ bi, const float* __restrict__ bh,
                       float* __restrict__ bias){
  int i = blockIdx.x*256 + threadIdx.x;
  if (i < 1024) bias[i] = bi[i] + bh[i];
}

__global__ void k_wlin(const float* __restrict__ Wl, u16* __restrict__ wlin){
  int i = blockIdx.x*256 + threadIdx.x;
  if (i >= 64*264) return;
  int col = i / 264, k = i % 264;
  wlin[i] = (k < 256) ? f2bf(Wl[col*256 + k]) : (u16)0;
}

// ---- x(B,C,F,T) -> y(n,t,c) bf16, n = b*257+f
__global__ void k_ytrans(const float* __restrict__ x, u16* __restrict__ ybuf){
  __shared__ u16 tile[64][257];
  int n = blockIdx.x, b = n / 257, f = n % 257, tid = threadIdx.x;
  for (int i = tid; i < 64*256; i += 256){
    int c = i >> 8, t = i & 255;
    tile[c][t] = f2bf(x[((size_t)(b*64 + c)*257 + f)*256 + t]);
  }
  __syncthreads();
  for (int i = tid; i < 256*64; i += 256){
    int t = i >> 6, c = i & 63;
    ybuf[((size_t)n*256 + t)*64 + c] = tile[c][t];
  }
}

// ---- xg chunk: xg[n,t,:] = y[n,t,:] @ W_ih^T + bias, stored lane-faithfully in
// the LSTM acc-fragment layout: xgs[(((g*CH + (t-t0))*8 + w)*64 + lane)*32 + ct*2p..]
__global__ __launch_bounds__(512) void k_xgates(const u16* __restrict__ wpack,
      const float* __restrict__ bias, const u16* __restrict__ ybuf,
      u16* __restrict__ xgs, int t0, int CH){
  __shared__ u16 yt[16*16*72];          // [tt][seq][72]
  const int g = blockIdx.x, tb = blockIdx.y*16, n0 = g*16;
  const int tid = threadIdx.x, lane = tid & 63, w = tid >> 6;
  const int l15 = lane & 15, q = lane >> 4;

  v8bf wf[2][8];                        // W_ih = kt8,9 of wpack
  #pragma unroll
  for (int kf = 0; kf < 2; ++kf)
    #pragma unroll
    for (int ct = 0; ct < 8; ++ct)
      wf[kf][ct] = *(const v8bf*)(wpack + (((8 + kf)*8 + w)*8 + ct)*512 + lane*8);
  float biasr[8];
  #pragma unroll
  for (int ct = 0; ct < 8; ++ct)
    biasr[ct] = bias[(ct >> 1)*256 + w*32 + (ct & 1)*16 + l15];

  #pragma unroll
  for (int s = 0; s < 4; ++s){          // stage y: 16 seqs x 16 t x 64 c
    int i = tid + s*512;
    int seq = i >> 7, tt = (i >> 3) & 15, c8 = i & 7;
    uint4 v = {0u,0u,0u,0u};
    if (n0 + seq < NSEQ)
      v = *(const uint4*)(ybuf + ((size_t)(n0 + seq)*TT + t0 + tb + tt)*64 + c8*8);
    *(uint4*)(yt + tt*1152 + seq*72 + c8*8) = v;
  }
  __syncthreads();

  for (int tt = 0; tt < 16; ++tt){
    f32x4 acc[8];
    #pragma unroll
    for (int ct = 0; ct < 8; ++ct)
      acc[ct] = (f32x4){biasr[ct], biasr[ct], biasr[ct], biasr[ct]};
    v8bf a0 = *(const v8bf*)(yt + tt*1152 + l15*72 + q*8);
    v8bf a1 = *(const v8bf*)(yt + tt*1152 + l15*72 + 32 + q*8);
    #pragma unroll
    for (int ct = 0; ct < 8; ++ct){
      acc[ct] = __builtin_amdgcn_mfma_f32_16x16x32_bf16(a0, wf[0][ct], acc[ct], 0, 0, 0);
      acc[ct] = __builtin_amdgcn_mfma_f32_16x16x32_bf16(a1, wf[1][ct], acc[ct], 0, 0, 0);
    }
    unsigned dw[16];
    #pragma unroll
    for (int ct = 0; ct < 8; ++ct)
      #pragma unroll
      for (int p = 0; p < 2; ++p)
        dw[ct*2 + p] = (unsigned)f2bf(acc[ct][2*p]) | ((unsigned)f2bf(acc[ct][2*p + 1]) << 16);
    u16* dst = xgs + ((((size_t)g*CH + tb + tt)*8 + w)*64 + lane)*32;
    *(uint4*)(dst +  0) = (uint4){dw[0], dw[1], dw[2], dw[3]};
    *(uint4*)(dst +  8) = (uint4){dw[4], dw[5], dw[6], dw[7]};
    *(uint4*)(dst + 16) = (uint4){dw[8], dw[9], dw[10], dw[11]};
    *(uint4*)(dst + 24) = (uint4){dw[12], dw[13], dw[14], dw[15]};
  }
}

// ---- xg-path LSTM chunk: 65 blocks x 512 thr, K=256, steps [t0, t0+CH).
// kt0..3 AGPR (128/wave), kt4,5 LDS, kt6,7 streamed with stall-free gaps:
// kt7 refilled at kt6-consume (gap ~1300cyc), kt6' refilled pre-cell (gap ~2400).
__global__ __launch_bounds__(512, 2) void k_lstm_xg(const u16* __restrict__ wpack,
      const u16* __restrict__ xgs, u16* __restrict__ hbuf, float* __restrict__ cbuf,
      int t0, int CH){
  extern __shared__ char smem[];
  char* lA = smem;                              // [2][16][XROW]
  u16*  lW = (u16*)(smem + 2*XG_A);             // kt4,5 slabs
  const int tid = threadIdx.x, lane = tid & 63, w = tid >> 6;
  const int g = blockIdx.x, n0 = g*16;
  const int l15 = lane & 15, q = lane >> 4;
  const int srow = tid >> 5, schunk = tid & 31;

  v8bf wreg[4][8];                              // kt0..3 -> AGPR via "a" uses
  #pragma unroll
  for (int kt = 0; kt < 4; ++kt)
    #pragma unroll
    for (int ct = 0; ct < 8; ++ct)
      wreg[kt][ct] = *(const v8bf*)(wpack + ((kt*8 + w)*8 + ct)*512 + lane*8);
  { // LDS-resident kt4,5
    const uint4* src = (const uint4*)(wpack + 4*SLABE);
    uint4* dst = (uint4*)lW;
    for (int i = tid; i < (2*SLABE)/8; i += 512) dst[i] = src[i];
  }
  { // stage A[t0&1] = h(t0-1) (or zeros for t0=0)
    uint4 hv = {0u,0u,0u,0u};
    if (t0 > 0 && n0 + srow < NSEQ)
      hv = *(const uint4*)(hbuf + ((size_t)(n0 + srow)*TT + (t0 - 1))*HH + schunk*8);
    *(uint4*)(lA + (t0 & 1)*XG_A + srow*XROW + schunk*16) = hv;
  }
  f32x4 creg[2];
  creg[0] = (f32x4){0.f,0.f,0.f,0.f};
  creg[1] = (f32x4){0.f,0.f,0.f,0.f};
  if (t0 > 0){
    #pragma unroll
    for (int u = 0; u < 2; ++u)
      #pragma unroll
      for (int j = 0; j < 4; ++j){
        int row = 4*q + j, unit = w*32 + u*16 + l15;
        if (n0 + row < NSEQ) creg[u][j] = cbuf[(size_t)(n0 + row)*HH + unit];
      }
  }
  __syncthreads();

  const u16* wp = wpack;           // opaque-refreshed (defeats LICM on refills)

  v8bf sbuf[8];
  uint4 xgv[4];
  { // prologue: kt6 + xg(t0)
    const u16* wpw0 = wp + w*4096 + lane*8;
    #pragma unroll
    for (int ct = 0; ct < 8; ++ct) sbuf[ct] = *(const v8bf*)(wpw0 + 6*SLABE + ct*512);
    const u16* xb = xgs + ((((size_t)g*CH + 0)*8 + w)*64 + lane)*32;
    xgv[0] = *(const uint4*)(xb +  0);
    xgv[1] = *(const uint4*)(xb +  8);
    xgv[2] = *(const uint4*)(xb + 16);
    xgv[3] = *(const uint4*)(xb + 24);
  }

  for (int t = t0; t < t0 + CH; ++t){
    char* Acur = lA + (t & 1)*XG_A;
    char* Anxt = lA + ((t + 1) & 1)*XG_A;
    asm("" : "+s"(wp));
    const u16* wpw = wp + w*4096 + lane*8;

    // h(t-1) writeout (t==t0 handled by previous launch's epilogue)
    if (t > t0 && n0 + srow < NSEQ){
      uint4 hv = *(const uint4*)(Acur + srow*XROW + schunk*16);
      *(uint4*)(hbuf + ((size_t)(n0 + srow)*TT + (t - 1))*HH + schunk*8) = hv;
    }

    // acc init from xg fragment (bf16 -> f32 by shift)
    f32x4 acc[8];
    #pragma unroll
    for (int ct = 0; ct < 8; ++ct){
      #pragma unroll
      for (int p = 0; p < 2; ++p){
        unsigned u = ((const unsigned*)&xgv[(ct*2 + p) >> 2])[(ct*2 + p) & 3];
        acc[ct][2*p]     = __builtin_bit_cast(float, u << 16);
        acc[ct][2*p + 1] = __builtin_bit_cast(float, u & 0xffff0000u);
      }
    }
    asm volatile("s_nop 1"
      : "+v"(acc[0]), "+v"(acc[1]), "+v"(acc[2]), "+v"(acc[3]),
        "+v"(acc[4]), "+v"(acc[5]), "+v"(acc[6]), "+v"(acc[7]));

    // prefetch xg(t+1) (in flight across the whole step)
    if (t + 1 < t0 + CH){
      const u16* xb = xgs + ((((size_t)g*CH + (t + 1 - t0))*8 + w)*64 + lane)*32;
      xgv[0] = *(const uint4*)(xb +  0);
      xgv[1] = *(const uint4*)(xb +  8);
      xgv[2] = *(const uint4*)(xb + 16);
      xgv[3] = *(const uint4*)(xb + 24);
    }
    __builtin_amdgcn_sched_barrier(0);

    #define AFRAGX(kt) (*(const v8bf*)(Acur + l15*XROW + (kt)*64 + q*16))
    #define LFRAGX(kt,ct) (*(const v8bf*)(lW + (((kt)-4)*8 + w)*4096 + (ct)*512 + lane*8))

    { v8bf a = AFRAGX(6);                        // kt6 (prefetched last step) -> refill kt7
      #pragma unroll
      for (int ct = 0; ct < 8; ++ct) mfma_v(acc[ct], a, sbuf[ct]);
      #pragma unroll
      for (int ct = 0; ct < 8; ++ct) sbuf[ct] = *(const v8bf*)(wpw + 7*SLABE + ct*512);
      __builtin_amdgcn_sched_barrier(0); }
    { v8bf a = AFRAGX(0);                        // kt0..3 (AGPR)
      #pragma unroll
      for (int ct = 0; ct < 8; ++ct) mfma_a(acc[ct], a, wreg[0][ct]); }
    { v8bf a = AFRAGX(1);
      #pragma unroll
      for (int ct = 0; ct < 8; ++ct) mfma_a(acc[ct], a, wreg[1][ct]); }
    { v8bf a = AFRAGX(2);
      #pragma unroll
      for (int ct = 0; ct < 8; ++ct) mfma_a(acc[ct], a, wreg[2][ct]); }
    { v8bf a = AFRAGX(3);
      #pragma unroll
      for (int ct = 0; ct < 8; ++ct) mfma_a(acc[ct], a, wreg[3][ct]); }
    { v8bf a = AFRAGX(4);                        // kt4 (LDS)
      #pragma unroll
      for (int ct = 0; ct < 8; ++ct) mfma_v(acc[ct], a, LFRAGX(4,ct)); }
    { v8bf a = AFRAGX(5);                        // kt5 (LDS)
      #pragma unroll
      for (int ct = 0; ct < 8; ++ct) mfma_v(acc[ct], a, LFRAGX(5,ct)); }
    { v8bf a = AFRAGX(7);                        // kt7 -> refill kt6 for t+1 (hides under cell)
      #pragma unroll
      for (int ct = 0; ct < 8; ++ct) mfma_v(acc[ct], a, sbuf[ct]);
      #pragma unroll
      for (int ct = 0; ct < 8; ++ct) sbuf[ct] = *(const v8bf*)(wpw + 6*SLABE + ct*512);
      __builtin_amdgcn_sched_barrier(0); }

    asm volatile("s_nop 7\n\ts_nop 7\n\ts_nop 7"
      : "+v"(acc[0]), "+v"(acc[1]), "+v"(acc[2]), "+v"(acc[3]),
        "+v"(acc[4]), "+v"(acc[5]), "+v"(acc[6]), "+v"(acc[7]));

    // cell: lane owns units w*32+u*16+l15, rows 4q+j
    #pragma unroll
    for (int u = 0; u < 2; ++u){
      #pragma unroll
      for (int j = 0; j < 4; ++j){
        float xi = acc[0 + u][j], xf = acc[2 + u][j], xg = acc[4 + u][j], xo = acc[6 + u][j];
        float cv = sigm(xf)*creg[u][j] + sigm(xi)*tanh_f(xg);
        float hv = sigm(xo)*tanh_f(cv);
        creg[u][j] = cv;
        int row = 4*q + j, unit = w*32 + u*16 + l15;
        *(u16*)(Anxt + row*XROW + unit*2) = f2bf(hv);
      }
    }
    soft_barrier();
  }
  { // epilogue: h(t0+CH-1) writeout + c checkpoint
    char* Afin = lA + ((t0 + CH) & 1)*XG_A;
    if (n0 + srow < NSEQ){
      uint4 hv = *(const uint4*)(Afin + srow*XROW + schunk*16);
      *(uint4*)(hbuf + ((size_t)(n0 + srow)*TT + (t0 + CH - 1))*HH + schunk*8) = hv;
    }
    #pragma unroll
    for (int u = 0; u < 2; ++u)
      #pragma unroll
      for (int j = 0; j < 4; ++j){
        int row = 4*q + j, unit = w*32 + u*16 + l15;
        if (n0 + row < NSEQ) cbuf[(size_t)(n0 + row)*HH + unit] = creg[u][j];
      }
  }
}

// ---- fallback LSTM (r10 verbatim, proven 1113-1125 us)
__global__ __launch_bounds__(512, 2) void k_lstm_fb(const u16* __restrict__ wpack,
      const float* __restrict__ bias, const u16* __restrict__ ybuf,
      u16* __restrict__ hbuf){
  extern __shared__ char smem[];
  char* lA = smem;
  u16*  lW = (u16*)(smem + 2*16*AROWB);
  const int tid = threadIdx.x, lane = tid & 63, w = tid >> 6;
  const int n0 = blockIdx.x * 16;
  const int l15 = lane & 15, q = lane >> 4;
  const int srow = tid >> 5, schunk = tid & 31;

  v8bf wreg[4][8];
  #pragma unroll
  for (int kt = 0; kt < 4; ++kt)
    #pragma unroll
    for (int ct = 0; ct < 8; ++ct)
      wreg[kt][ct] = *(const v8bf*)(wpack + ((kt*8 + w)*8 + ct)*512 + lane*8);
  {
    const uint4* src = (const uint4*)(wpack + 4*SLABE);
    uint4* dst = (uint4*)lW;
    for (int i = tid; i < (2*SLABE)/8; i += 512) dst[i] = src[i];
  }
  float biasr[8];
  #pragma unroll
  for (int ct = 0; ct < 8; ++ct)
    biasr[ct] = bias[(ct >> 1)*256 + w*32 + (ct & 1)*16 + l15];
  {
    unsigned* z = (unsigned*)lA;
    for (int i = tid; i < (2*16*AROWB)/4; i += 512) z[i] = 0;
  }
  __syncthreads();
  {
    unsigned v = 0;
    if (n0 + srow < NSEQ)
      v = *(const unsigned*)(ybuf + ((size_t)(n0 + srow)*TT + 0)*64 + schunk*2);
    *(unsigned*)(lA + srow*AROWB + 512 + schunk*4) = v;
  }
  f32x4 creg[2];
  creg[0] = (f32x4){0.f,0.f,0.f,0.f};
  creg[1] = (f32x4){0.f,0.f,0.f,0.f};
  __syncthreads();

  const u16* wp = wpack;
  v8bf sbuf[8];
  {
    const u16* wpw0 = wp + w*4096 + lane*8;
    #pragma unroll
    for (int ct = 0; ct < 8; ++ct) sbuf[ct] = *(const v8bf*)(wpw0 + 6*SLABE + ct*512);
  }

  for (int t = 0; t < TT; ++t){
    char* Acur = lA + (t & 1)*16*AROWB;
    char* Anxt = lA + ((t + 1) & 1)*16*AROWB;
    asm("" : "+s"(wp));
    const u16* wpw = wp + w*4096 + lane*8;

    unsigned yv = 0;
    if (t + 1 < TT && n0 + srow < NSEQ)
      yv = *(const unsigned*)(ybuf + ((size_t)(n0 + srow)*TT + (t + 1))*64 + schunk*2);

    if (t >= 1 && n0 + srow < NSEQ){
      uint4 hv = *(const uint4*)(Acur + srow*AROWB + schunk*16);
      *(uint4*)(hbuf + ((size_t)(n0 + srow)*TT + (t - 1))*HH + schunk*8) = hv;
    }

    f32x4 acc[8];
    #pragma unroll
    for (int ct = 0; ct < 8; ++ct)
      acc[ct] = (f32x4){biasr[ct], biasr[ct], biasr[ct], biasr[ct]};
    asm volatile("s_nop 1"
      : "+v"(acc[0]), "+v"(acc[1]), "+v"(acc[2]), "+v"(acc[3]),
        "+v"(acc[4]), "+v"(acc[5]), "+v"(acc[6]), "+v"(acc[7]));

    #define AFRAG(kt) (*(const v8bf*)(Acur + l15*AROWB + (kt)*64 + q*16))
    #define LFRAG(kt,ct) (*(const v8bf*)(lW + (((kt)-4)*8 + w)*4096 + (ct)*512 + lane*8))

    { v8bf a = AFRAG(0);
      #pragma unroll
      for (int ct = 0; ct < 8; ++ct) mfma_a(acc[ct], a, wreg[0][ct]); }
    { v8bf a = AFRAG(1);
      #pragma unroll
      for (int ct = 0; ct < 8; ++ct) mfma_a(acc[ct], a, wreg[1][ct]); }
    { v8bf a = AFRAG(6);
      #pragma unroll
      for (int ct = 0; ct < 8; ++ct) mfma_v(acc[ct], a, sbuf[ct]);
      #pragma unroll
      for (int ct = 0; ct < 8; ++ct) sbuf[ct] = *(const v8bf*)(wpw + 7*SLABE + ct*512);
      __builtin_amdgcn_sched_barrier(0); }
    { v8bf a = AFRAG(2);
      #pragma unroll
      for (int ct = 0; ct < 8; ++ct) mfma_a(acc[ct], a, wreg[2][ct]); }
    { v8bf a = AFRAG(3);
      #pragma unroll
      for (int ct = 0; ct < 8; ++ct) mfma_a(acc[ct], a, wreg[3][ct]); }
    { v8bf a = AFRAG(7);
      #pragma unroll
      for (int ct = 0; ct < 8; ++ct) mfma_v(acc[ct], a, sbuf[ct]);
      #pragma unroll
      for (int ct = 0; ct < 8; ++ct) sbuf[ct] = *(const v8bf*)(wpw + 8*SLABE + ct*512);
      __builtin_amdgcn_sched_barrier(0); }
    { v8bf a = AFRAG(4);
      #pragma unroll
      for (int ct = 0; ct < 8; ++ct) mfma_v(acc[ct], a, LFRAG(4,ct)); }
    { v8bf a = AFRAG(8);
      #pragma unroll
      for (int ct = 0; ct < 8; ++ct) mfma_v(acc[ct], a, sbuf[ct]);
      #pragma unroll
      for (int ct = 0; ct < 8; ++ct) sbuf[ct] = *(const v8bf*)(wpw + 9*SLABE + ct*512);
      __builtin_amdgcn_sched_barrier(0); }
    { v8bf a = AFRAG(5);
      #pragma unroll
      for (int ct = 0; ct < 8; ++ct) mfma_v(acc[ct], a, LFRAG(5,ct)); }
    { v8bf a = AFRAG(9);
      #pragma unroll
      for (int ct = 0; ct < 8; ++ct) mfma_v(acc[ct], a, sbuf[ct]);
      #pragma unroll
      for (int ct = 0; ct < 8; ++ct) sbuf[ct] = *(const v8bf*)(wpw + 6*SLABE + ct*512);
      __builtin_amdgcn_sched_barrier(0); }

    asm volatile("s_nop 7\n\ts_nop 7\n\ts_nop 7"
      : "+v"(acc[0]), "+v"(acc[1]), "+v"(acc[2]), "+v"(acc[3]),
        "+v"(acc[4]), "+v"(acc[5]), "+v"(acc[6]), "+v"(acc[7]));

    #pragma unroll
    for (int u = 0; u < 2; ++u){
      #pragma unroll
      for (int j = 0; j < 4; ++j){
        float xi = acc[0 + u][j], xf = acc[2 + u][j], xg = acc[4 + u][j], xo = acc[6 + u][j];
        float cv = sigm(xf)*creg[u][j] + sigm(xi)*tanh_f(xg);
        float hv = sigm(xo)*tanh_f(cv);
        creg[u][j] = cv;
        int row = 4*q + j, unit = w*32 + u*16 + l15;
        *(u16*)(Anxt + row*AROWB + unit*2) = f2bf(hv);
      }
    }
    if (t + 1 < TT)
      *(unsigned*)(Anxt + srow*AROWB + 512 + schunk*4) = yv;
    soft_barrier();
  }
  {
    char* Afin = lA + (TT & 1)*16*AROWB;
    if (n0 + srow < NSEQ){
      uint4 hv = *(const uint4*)(Afin + srow*AROWB + schunk*16);
      *(uint4*)(hbuf + ((size_t)(n0 + srow)*TT + (TT - 1))*HH + schunk*8) = hv;
    }
  }
}

// ---- out = h @ W_lin^T + b_lin, written as (B,OUT,F,T)
__global__ __launch_bounds__(256) void k_outproj(const u16* __restrict__ hbuf,
      const u16* __restrict__ wlin, const float* __restrict__ blin,
      float* __restrict__ out){
  extern __shared__ char smem[];
  u16* sA = (u16*)smem;
  u16* sB = (u16*)(smem + 128*264*2);
  const int n = blockIdx.x, th = blockIdx.y, t0 = th*128;
  const int b = n / 257, f = n % 257;
  const int tid = threadIdx.x, lane = tid & 63, wv = tid >> 6;

  for (int i = tid; i < 128*32; i += 256){
    int r = i >> 5, part = i & 31;
    *(uint4*)(sA + r*264 + part*8) =
        *(const uint4*)(hbuf + ((size_t)n*TT + t0 + r)*HH + part*8);
  }
  for (int i = tid; i < (64*264)/2; i += 256)
    ((unsigned*)sB)[i] = ((const unsigned*)wlin)[i];
  __syncthreads();

  f32x4 acc[2][4];
  #pragma unroll
  for (int m = 0; m < 2; ++m)
    #pragma unroll
    for (int nt = 0; nt < 4; ++nt){
      float bv = blin[nt*16 + (lane & 15)];
      acc[m][nt] = (f32x4){bv, bv, bv, bv};
    }
  const int khi = (lane >> 4) * 8;
  #pragma unroll
  for (int kt = 0; kt < 8; ++kt){
    v8bf av[2];
    #pragma unroll
    for (int m = 0; m < 2; ++m){
      int mt = wv*2 + m;
      av[m] = *(const v8bf*)(sA + (mt*16 + (lane & 15))*264 + kt*32 + khi);
    }
    #pragma unroll
    for (int nt = 0; nt < 4; ++nt){
      v8bf bv = *(const v8bf*)(sB + (nt*16 + (lane & 15))*264 + kt*32 + khi);
      #pragma unroll
      for (int m = 0; m < 2; ++m)
        acc[m][nt] = __builtin_amdgcn_mfma_f32_16x16x32_bf16(av[m], bv, acc[m][nt], 0, 0, 0);
    }
  }
  #pragma unroll
  for (int m = 0; m < 2; ++m){
    int mt = wv*2 + m;
    #pragma unroll
    for (int nt = 0; nt < 4; ++nt){
      int o = nt*16 + (lane & 15);
      int tb = t0 + mt*16 + 4*(lane >> 4);
      *(f32x4*)(out + (((size_t)b*64 + o)*257 + f)*TT + tb) = acc[m][nt];
    }
  }
}

extern "C" void kernel_launch(void* const* d_in, const int* in_sizes, int n_in,
                              void* d_out, int out_size, void* d_ws, size_t ws_size,
                              hipStream_t stream) {
  const float* x   = (const float*)d_in[0];
  const float* Wih = (const float*)d_in[1];
  const float* Whh = (const float*)d_in[2];
  const float* bih = (const float*)d_in[3];
  const float* bhh = (const float*)d_in[4];
  const float* Wl  = (const float*)d_in[5];
  const float* bl  = (const float*)d_in[6];
  float* out = (float*)d_out;

  char* p = (char*)d_ws;
  u16*   wpack = (u16*)p;   p += 655360;
  float* bias  = (float*)p; p += 4096;
  u16*   wlin  = (u16*)p;   p += 33792;
  float* cbuf  = (float*)p; p += (size_t)NSEQ*HH*4;      // 1,052,672
  u16*   ybuf  = (u16*)p;   p += (size_t)NSEQ*TT*CC*2;   // 33,685,504
  u16*   hbuf  = (u16*)p;   p += (size_t)NSEQ*TT*HH*2;   // 134,742,016
  u16*   xgs   = (u16*)p;
  const size_t BASE = (size_t)(p - (char*)d_ws);          // 170,173,440

  int CH = 0;
  if      (ws_size >= BASE + 65ull*64*32768) CH = 64;
  else if (ws_size >= BASE + 65ull*32*32768) CH = 32;
  else if (ws_size >= BASE + 65ull*16*32768) CH = 16;

  hipFuncSetAttribute((const void*)k_lstm_xg, hipFuncAttributeMaxDynamicSharedMemorySize, XG_LDS);
  hipFuncSetAttribute((const void*)k_lstm_fb, hipFuncAttributeMaxDynamicSharedMemorySize, FB_LDS);
  hipFuncSetAttribute((const void*)k_outproj, hipFuncAttributeMaxDynamicSharedMemorySize, OUTP_LDS);

  k_pack_w <<<1280, 256, 0, stream>>>(Whh, Wih, wpack);
  k_bias   <<<4,    256, 0, stream>>>(bih, bhh, bias);
  k_wlin   <<<66,   256, 0, stream>>>(Wl, wlin);
  k_ytrans <<<1028, 256, 0, stream>>>(x, ybuf);

  if (CH) {
    for (int t0 = 0; t0 < TT; t0 += CH){
      k_xgates <<<dim3(65, CH/16), 512, 0, stream>>>(wpack, bias, ybuf, xgs, t0, CH);
      k_lstm_xg<<<65, 512, XG_LDS, stream>>>(wpack, xgs, hbuf, cbuf, t0, CH);
    }
  } else {
    k_lstm_fb<<<65, 512, FB_LDS, stream>>>(wpack, bias, ybuf, hbuf);
  }
  k_outproj<<<dim3(1028, 2), 256, OUTP_LDS, stream>>>(hbuf, wlin, bl, out);
}